// Round 2
// baseline (13154.993 us; speedup 1.0000x reference)
//
#include <hip/hip_runtime.h>
#include <hip/hip_bf16.h>
#include <stdint.h>
#include <string.h>

// ---------------- problem constants ----------------
// B=64, T=256, D=H=256, L=50, O=2; K = 2H = 512 (concat [h_in; h_prev]); G = 4H = 1024
#define NB   64
#define NT   256
#define NH   256
#define NL   50
#define NK   512
#define NG   1024

typedef __attribute__((ext_vector_type(8)))  short   short8;
typedef __attribute__((ext_vector_type(8)))  __bf16  bf16x8;
typedef __attribute__((ext_vector_type(4)))  float   float4v;

__device__ __forceinline__ unsigned short f2bf(float f) {
  union { float f; uint32_t u; } v; v.f = f;
  uint32_t u = v.u;
  uint32_t r = (u + 0x7FFFu + ((u >> 16) & 1u)) >> 16;   // RNE
  return (unsigned short)r;
}
__device__ __forceinline__ float bf2f(unsigned short s) {
  union { uint32_t u; float f; } v; v.u = ((uint32_t)s) << 16;
  return v.f;
}
__device__ __forceinline__ float sigmoidf_(float x) { return 1.0f / (1.0f + expf(-x)); }

// ---------------- workspace layout (bytes) ----------------
// Wswz : 50*1024*512 bf16 = 52,428,800
// Bias : 50*1024 f32      =    204,800
// Xbf  : 256*64*256 bf16  =  8,388,608   ([t][b][d])
// Hring: 4*50*64*256 bf16 =  6,553,600   (ring slot = t&3)
// Y    : 256*64*256 bf16  =  8,388,608   ([t][b][h], layer-49 h)
// prod : 50*256 int       =     51,200
// cons : 50*256 int       =     51,200
#define OFF_WSWZ  0
#define OFF_BIAS  52428800
#define OFF_XBF   52633600
#define OFF_HRING 61022208
#define OFF_Y     67575808
#define OFF_PROD  75964416
#define OFF_CONS  76015616
// total: 76,066,816 bytes

// ---------------- preprocessing ----------------
// Weight swizzle: Wswz[idx], idx = ((((l*16+c)*4+q)*16+kt)*64+lam)*8+j
// holds Wcat[g = q*256 + c*16 + (lam&15)][k = kt*32 + (lam>>4)*8 + j] as bf16,
// where Wcat = [W_ih | W_hh] along k. Exact MFMA B-fragment lane order.
__global__ void prep_w(const float* __restrict__ Wih, const float* __restrict__ Whh,
                       unsigned short* __restrict__ Wswz) {
  int idx = blockIdx.x * 256 + threadIdx.x;        // 26,214,400 total
  int j   = idx & 7;
  int lam = (idx >> 3) & 63;
  int kt  = (idx >> 9) & 15;
  int q   = (idx >> 13) & 3;
  int c   = (idx >> 15) & 15;
  int l   = idx >> 19;
  int k   = kt * 32 + (lam >> 4) * 8 + j;
  int g   = q * 256 + c * 16 + (lam & 15);
  float v = (k < 256) ? Wih[(l * NG + g) * 256 + k]
                      : Whh[(l * NG + g) * 256 + (k - 256)];
  Wswz[idx] = f2bf(v);
}

__global__ void prep_bias(const float* __restrict__ bih, const float* __restrict__ bhh,
                          float* __restrict__ Bias) {
  int idx = blockIdx.x * 256 + threadIdx.x;        // 51,200 total
  int col = idx & 15; int q = (idx >> 4) & 3; int c = (idx >> 6) & 15; int l = idx >> 10;
  int g = q * 256 + c * 16 + col;
  Bias[idx] = bih[l * NG + g] + bhh[l * NG + g];
}

__global__ void prep_x(const float* __restrict__ x, unsigned short* __restrict__ Xbf) {
  int idx = blockIdx.x * 256 + threadIdx.x;        // 4,194,304 total
  int d = idx & 255; int t = (idx >> 8) & 255; int b = idx >> 16;
  Xbf[(t * NB + b) * 256 + d] = f2bf(x[idx]);
}

__global__ void zero_flags(int* __restrict__ p) {
  p[blockIdx.x * 256 + threadIdx.x] = 0;           // 25,600 ints (prod+cons contiguous)
}

// ---------------- sync helpers ----------------
__device__ __forceinline__ void wait_ge4(int* p) {
  while (__hip_atomic_load(p, __ATOMIC_ACQUIRE, __HIP_MEMORY_SCOPE_AGENT) < 4)
    __builtin_amdgcn_s_sleep(2);
}
__device__ __forceinline__ void signal_add1(int* p) {
  __hip_atomic_fetch_add(p, 1, __ATOMIC_RELEASE, __HIP_MEMORY_SCOPE_AGENT);
}

// ---------------- persistent LSTM kernel ----------------
// 200 WGs (4 per layer), 256 threads, 1 WG/CU (co-resident: 200 <= 256 CUs,
// 64KB LDS + ~390 VGPR force 1 WG/CU). Each wave owns one 64-gate chunk with
// its 64KB weight slab held in 256 VGPRs for all 256 timesteps. h exchanged
// through a depth-4 global ring with prod/cons counters (device scope).
__global__ __launch_bounds__(256, 1) void lstm_persistent(
    const unsigned short* __restrict__ Wswz,
    const float* __restrict__ Bias,
    const unsigned short* __restrict__ Xbf,
    unsigned short* __restrict__ Hring,
    unsigned short* __restrict__ Y,
    int* __restrict__ prod,
    int* __restrict__ cons) {
  int l   = blockIdx.x >> 2;
  int w   = blockIdx.x & 3;
  int tid = threadIdx.x;

  __shared__ unsigned short hc[64 * 512];   // 64 KB; phys unit = b*64 + (ku ^ (b&7))

  int wave = tid >> 6;
  int lane = tid & 63;
  int c    = w * 4 + wave;          // chunk 0..15 -> hidden units [c*16, c*16+16)
  int colg = lane & 15;
  int quad = lane >> 4;

  // ---- one-time: weights into registers (64 x bf16x8 = 256 VGPRs/lane) ----
  bf16x8 wreg[64];
  {
    const unsigned short* wp = Wswz + (size_t)(l * 16 + c) * 32768 + lane * 8;
#pragma unroll
    for (int i = 0; i < 64; ++i)
      wreg[i] = *(const bf16x8*)(wp + i * 512);
  }
  float bv[4];
  {
    const float* bp = Bias + l * NG + c * 64;
#pragma unroll
    for (int q = 0; q < 4; ++q) bv[q] = bp[q * 16 + colg];
  }

  float cr[4][4] = {};              // cell state, registers (b = m*16+quad*4+r, j fixed)
  int j = c * 16 + colg;
  bool last = (l == NL - 1);

  for (int t = 0; t < NT; ++t) {
    // ---- dependency waits (all threads spin; each gets its own acquire) ----
    if (l > 0)               wait_ge4(&prod[(l - 1) * NT + t]);       // h_in ready
    if (t > 0)               wait_ge4(&prod[l * NT + (t - 1)]);       // siblings' h_prev
    if (!last && t >= 4)     wait_ge4(&cons[l * NT + (t - 4)]);       // ring backpressure

    const unsigned short* In = (l == 0)
        ? (Xbf + t * (NB * 256))
        : (Hring + (((t & 3) * NL + (l - 1)) * NB) * 256);
    const unsigned short* Pv = Hring + ((((t - 1) & 3) * NL + l) * NB) * 256;
    bool t0 = (t == 0);

    // ---- stage h_cat[64][512] into LDS (coalesced 16B loads) ----
    for (int i = 0; i < 16; ++i) {
      int u  = i * 256 + tid;
      int b  = u >> 6;
      int ku = u & 63;
      int k  = ku * 8;
      short8 val;
      if (k < 256)       val = *(const short8*)(In + b * 256 + k);
      else if (!t0)      val = *(const short8*)(Pv + b * 256 + (k - 256));
      else               val = short8{0, 0, 0, 0, 0, 0, 0, 0};
      *(short8*)(hc + (b * 64 + (ku ^ (b & 7))) * 8) = val;
    }
    __syncthreads();
    if (tid == 0 && l > 0) signal_add1(&cons[(l - 1) * NT + t]);      // upstream slot consumed

    // ---- GEMM: 256 MFMAs/wave, weights from registers ----
    float4v acc[4][4];
#pragma unroll
    for (int q = 0; q < 4; ++q) {
      float4v f4 = {bv[q], bv[q], bv[q], bv[q]};
#pragma unroll
      for (int m = 0; m < 4; ++m) acc[m][q] = f4;
    }
#pragma unroll
    for (int kt = 0; kt < 16; ++kt) {
      bf16x8 a[4];
#pragma unroll
      for (int m = 0; m < 4; ++m) {
        int row = m * 16 + colg;
        int ku  = (kt * 4 + quad) ^ (colg & 7);
        a[m] = *(const bf16x8*)(hc + (row * 64 + ku) * 8);
      }
#pragma unroll
      for (int m = 0; m < 4; ++m)
#pragma unroll
        for (int q = 0; q < 4; ++q)
          acc[m][q] = __builtin_amdgcn_mfma_f32_16x16x32_bf16(a[m], wreg[q * 16 + kt], acc[m][q], 0, 0, 0);
    }

    // ---- epilogue: gates -> c,h (C/D layout: col=lane&15, row=quad*4+reg) ----
    unsigned short* Hout = Hring + (((t & 3) * NL + l) * NB) * 256;
    unsigned short* Yout = Y + (t * NB) * 256;
#pragma unroll
    for (int m = 0; m < 4; ++m) {
#pragma unroll
      for (int r = 0; r < 4; ++r) {
        int b = m * 16 + quad * 4 + r;
        float gi = sigmoidf_(acc[m][0][r]);
        float gf = sigmoidf_(acc[m][1][r]);
        float gg = tanhf(acc[m][2][r]);
        float go = sigmoidf_(acc[m][3][r]);
        float cn = gf * cr[m][r] + gi * gg;   // cr starts 0 => t=0 correct
        cr[m][r] = cn;
        float h = go * tanhf(cn);
        unsigned short hb = f2bf(h);
        Hout[b * 256 + j] = hb;
        if (last) Yout[b * 256 + j] = hb;
      }
    }
    __syncthreads();                           // all 4 waves' h stores drained
    if (tid == 0) signal_add1(&prod[l * NT + t]);
  }
}

// ---------------- final projection ----------------
__global__ void final_proj(const unsigned short* __restrict__ Y,
                           const float* __restrict__ Wout,
                           const float* __restrict__ bout,
                           float* __restrict__ out) {
  int t = blockIdx.x;
  int tid = threadIdx.x;            // 128 = 64 b * 2 o
  int b = tid >> 1, o = tid & 1;
  const unsigned short* yrow = Y + (t * NB + b) * 256;
  const float* wr = Wout + o * 256;
  float s = bout[o];
  for (int k = 0; k < 256; ++k) s += bf2f(yrow[k]) * wr[k];
  out[(b * NT + t) * 2 + o] = sigmoidf_(s);
}

extern "C" void kernel_launch(void* const* d_in, const int* in_sizes, int n_in,
                              void* d_out, int out_size, void* d_ws, size_t ws_size,
                              hipStream_t stream) {
  (void)in_sizes; (void)n_in; (void)out_size; (void)ws_size;
  const float* x    = (const float*)d_in[0];
  const float* Wih  = (const float*)d_in[1];
  const float* Whh  = (const float*)d_in[2];
  const float* bih  = (const float*)d_in[3];
  const float* bhh  = (const float*)d_in[4];
  const float* Wout = (const float*)d_in[5];
  const float* bout = (const float*)d_in[6];
  float* out = (float*)d_out;

  char* ws = (char*)d_ws;
  unsigned short* Wswz  = (unsigned short*)(ws + OFF_WSWZ);
  float*          Bias  = (float*)(ws + OFF_BIAS);
  unsigned short* Xbf   = (unsigned short*)(ws + OFF_XBF);
  unsigned short* Hring = (unsigned short*)(ws + OFF_HRING);
  unsigned short* Y     = (unsigned short*)(ws + OFF_Y);
  int*            prod  = (int*)(ws + OFF_PROD);
  int*            cons  = (int*)(ws + OFF_CONS);

  prep_w    <<<102400, 256, 0, stream>>>(Wih, Whh, Wswz);
  prep_bias <<<200,    256, 0, stream>>>(bih, bhh, Bias);
  prep_x    <<<16384,  256, 0, stream>>>(x, Xbf);
  zero_flags<<<100,    256, 0, stream>>>(prod);      // prod+cons contiguous, 25600 ints

  lstm_persistent<<<NL * 4, 256, 0, stream>>>(Wswz, Bias, Xbf, Hring, Y, prod, cons);

  final_proj<<<NT, 128, 0, stream>>>(Y, Wout, bout, out);
}

// Round 3
// 5333.163 us; speedup vs baseline: 2.4666x; 2.4666x over previous
//
#include <hip/hip_runtime.h>
#include <hip/hip_bf16.h>
#include <stdint.h>
#include <string.h>

// ---------------- problem constants ----------------
// B=64, T=256, D=H=256, L=50, O=2; K = 2H = 512 (concat [h_in; h_prev]); G = 4H = 1024
#define NB   64
#define NT   256
#define NH   256
#define NL   50
#define NK   512
#define NG   1024

typedef __attribute__((ext_vector_type(8)))  short   short8;
typedef __attribute__((ext_vector_type(8)))  __bf16  bf16x8;
typedef __attribute__((ext_vector_type(4)))  float   float4v;

__device__ __forceinline__ unsigned short f2bf(float f) {
  union { float f; uint32_t u; } v; v.f = f;
  uint32_t u = v.u;
  uint32_t r = (u + 0x7FFFu + ((u >> 16) & 1u)) >> 16;   // RNE
  return (unsigned short)r;
}
__device__ __forceinline__ float bf2f(unsigned short s) {
  union { uint32_t u; float f; } v; v.u = ((uint32_t)s) << 16;
  return v.f;
}
// fast, overflow-safe activations (tolerance 1e-2; v_exp/v_rcp ~1ulp)
__device__ __forceinline__ float sigmoid_f(float x) {
  return 1.0f / (1.0f + __expf(-x));          // exp(+big)->inf -> rcp -> 0: safe
}
__device__ __forceinline__ float tanh_f(float x) {
  float e = __expf(-2.0f * __builtin_fabsf(x));   // in (0,1]
  float r = (1.0f - e) / (1.0f + e);
  return __builtin_copysignf(r, x);
}

// ---------------- workspace layout (bytes) ----------------
#define OFF_WSWZ  0
#define OFF_BIAS  52428800
#define OFF_XBF   52633600
#define OFF_HRING 61022208
#define OFF_Y     67575808
#define OFF_PROD  75964416
#define OFF_CONS  76015616
// total: 76,066,816 bytes

// ---------------- preprocessing ----------------
// Weight swizzle: Wswz[idx], idx = ((((l*16+c)*4+q)*16+kt)*64+lam)*8+j
// holds Wcat[g = q*256 + c*16 + (lam&15)][k = kt*32 + (lam>>4)*8 + j] as bf16.
// Exact MFMA B-fragment lane order (verified by R1/R2 pass).
__global__ void prep_w(const float* __restrict__ Wih, const float* __restrict__ Whh,
                       unsigned short* __restrict__ Wswz) {
  int idx = blockIdx.x * 256 + threadIdx.x;        // 26,214,400 total
  int j   = idx & 7;
  int lam = (idx >> 3) & 63;
  int kt  = (idx >> 9) & 15;
  int q   = (idx >> 13) & 3;
  int c   = (idx >> 15) & 15;
  int l   = idx >> 19;
  int k   = kt * 32 + (lam >> 4) * 8 + j;
  int g   = q * 256 + c * 16 + (lam & 15);
  float v = (k < 256) ? Wih[(l * NG + g) * 256 + k]
                      : Whh[(l * NG + g) * 256 + (k - 256)];
  Wswz[idx] = f2bf(v);
}

__global__ void prep_bias(const float* __restrict__ bih, const float* __restrict__ bhh,
                          float* __restrict__ Bias) {
  int idx = blockIdx.x * 256 + threadIdx.x;        // 51,200 total
  int col = idx & 15; int q = (idx >> 4) & 3; int c = (idx >> 6) & 15; int l = idx >> 10;
  int g = q * 256 + c * 16 + col;
  Bias[idx] = bih[l * NG + g] + bhh[l * NG + g];
}

__global__ void prep_x(const float* __restrict__ x, unsigned short* __restrict__ Xbf) {
  int idx = blockIdx.x * 256 + threadIdx.x;        // 4,194,304 total
  int d = idx & 255; int t = (idx >> 8) & 255; int b = idx >> 16;
  Xbf[(t * NB + b) * 256 + d] = f2bf(x[idx]);
}

__global__ void zero_flags(int* __restrict__ p) {
  p[blockIdx.x * 256 + threadIdx.x] = 0;           // 25,600 ints (prod+cons contiguous)
}

// ---------------- persistent LSTM kernel ----------------
// Grid 256 (56 exit immediately): x=blockIdx&7 is the XCD (heuristic %8 mapping);
// XCD x hosts layers 7x..7x+6, 4 sibling WGs per layer co-located on one XCD.
// 82.9KB LDS forces 1 WG/CU -> all 200 workers co-resident, 1 wave/SIMD,
// 512-VGPR budget holds each wave's 64KB weight chunk for all 256 timesteps.
// Sync: leader thread (tid 0) polls flags with RELAXED agent loads, single
// acquire fence on success, __syncthreads broadcast. Producers: release add.
#define RSTRIDE 81   // LDS row stride in 16B units; 81 % 8 == 1 -> conflict-free
__global__ __launch_bounds__(256, 1) void lstm_persistent(
    const unsigned short* __restrict__ Wswz,
    const float* __restrict__ Bias,
    const unsigned short* __restrict__ Xbf,
    unsigned short* __restrict__ Hring,
    unsigned short* __restrict__ Y,
    int* __restrict__ prod,
    int* __restrict__ cons) {
  int xcd = blockIdx.x & 7;
  int jj  = blockIdx.x >> 3;
  int l   = xcd * 7 + (jj >> 2);
  int w   = jj & 3;
  if (jj >= 28 || l >= NL) return;     // 56 idle WGs exit
  int tid = threadIdx.x;

  __shared__ unsigned short hc[64 * RSTRIDE * 8];   // 82,944 B

  int wave = tid >> 6;
  int lane = tid & 63;
  int c    = w * 4 + wave;          // gate chunk 0..15 -> hidden units [c*16, c*16+16)
  int colg = lane & 15;
  int quad = lane >> 4;

  // ---- one-time: weights into registers (64 x bf16x8 = 256 VGPRs/lane) ----
  bf16x8 wreg[64];
  {
    const unsigned short* wp = Wswz + (size_t)(l * 16 + c) * 32768 + lane * 8;
#pragma unroll
    for (int i = 0; i < 64; ++i)
      wreg[i] = *(const bf16x8*)(wp + i * 512);
  }
  float bv[4];
  {
    const float* bp = Bias + l * NG + c * 64;
#pragma unroll
    for (int q = 0; q < 4; ++q) bv[q] = bp[q * 16 + colg];
  }

  float cr[4][4] = {};              // cell state in registers
  int j = c * 16 + colg;
  bool last = (l == NL - 1);

  for (int t = 0; t < NT; ++t) {
    // ---- leader-poll: relaxed loads, one acquire fence ----
    if (tid == 0) {
      int* f1 = (l > 0) ? &prod[(l - 1) * NT + t] : nullptr;
      int* f2 = (t > 0) ? &prod[l * NT + (t - 1)] : nullptr;
      int* f3 = (!last && t >= 4) ? &cons[l * NT + (t - 4)] : nullptr;
      for (;;) {
        int a1 = f1 ? __hip_atomic_load(f1, __ATOMIC_RELAXED, __HIP_MEMORY_SCOPE_AGENT) : 4;
        int a2 = f2 ? __hip_atomic_load(f2, __ATOMIC_RELAXED, __HIP_MEMORY_SCOPE_AGENT) : 4;
        int a3 = f3 ? __hip_atomic_load(f3, __ATOMIC_RELAXED, __HIP_MEMORY_SCOPE_AGENT) : 4;
        if (a1 >= 4 && a2 >= 4 && a3 >= 4) break;
      }
      __builtin_amdgcn_fence(__ATOMIC_ACQUIRE, "agent");
    }
    __syncthreads();

    const unsigned short* In = (l == 0)
        ? (Xbf + t * (NB * 256))
        : (Hring + (((t & 3) * NL + (l - 1)) * NB) * 256);
    const unsigned short* Pv = Hring + ((((t - 1) & 3) * NL + l) * NB) * 256;
    bool t0 = (t == 0);

    // ---- stage h_cat[64][512] into LDS (coalesced 16B loads) ----
    for (int i = 0; i < 16; ++i) {
      int u  = i * 256 + tid;
      int b  = u >> 6;
      int ku = u & 63;
      int k  = ku * 8;
      short8 val;
      if (k < 256)       val = *(const short8*)(In + b * 256 + k);
      else if (!t0)      val = *(const short8*)(Pv + b * 256 + (k - 256));
      else               val = short8{0, 0, 0, 0, 0, 0, 0, 0};
      *(short8*)(hc + (b * RSTRIDE + ku) * 8) = val;
    }
    __syncthreads();
    if (tid == 0 && l > 0)    // upstream slot consumed; no data published -> relaxed
      __hip_atomic_fetch_add(&cons[(l - 1) * NT + t], 1, __ATOMIC_RELAXED, __HIP_MEMORY_SCOPE_AGENT);

    // ---- GEMM: 256 MFMAs/wave, weights from registers ----
    float4v acc[4][4];
#pragma unroll
    for (int q = 0; q < 4; ++q) {
      float4v f4 = {bv[q], bv[q], bv[q], bv[q]};
#pragma unroll
      for (int m = 0; m < 4; ++m) acc[m][q] = f4;
    }
#pragma unroll
    for (int kt = 0; kt < 16; ++kt) {
      bf16x8 a[4];
#pragma unroll
      for (int m = 0; m < 4; ++m)
        a[m] = *(const bf16x8*)(hc + ((m * 16 + colg) * RSTRIDE + kt * 4 + quad) * 8);
#pragma unroll
      for (int m = 0; m < 4; ++m)
#pragma unroll
        for (int q = 0; q < 4; ++q)
          acc[m][q] = __builtin_amdgcn_mfma_f32_16x16x32_bf16(a[m], wreg[q * 16 + kt], acc[m][q], 0, 0, 0);
    }

    // ---- epilogue: gates -> c,h (C/D layout: col=lane&15, row=quad*4+reg) ----
    unsigned short* Hout = Hring + (((t & 3) * NL + l) * NB) * 256;
    unsigned short* Yout = Y + (t * NB) * 256;
#pragma unroll
    for (int m = 0; m < 4; ++m) {
#pragma unroll
      for (int r = 0; r < 4; ++r) {
        int b = m * 16 + quad * 4 + r;
        float gi = sigmoid_f(acc[m][0][r]);
        float gf = sigmoid_f(acc[m][1][r]);
        float gg = tanh_f(acc[m][2][r]);
        float go = sigmoid_f(acc[m][3][r]);
        float cn = gf * cr[m][r] + gi * gg;   // cr starts 0 => t=0 correct
        cr[m][r] = cn;
        float h = go * tanh_f(cn);
        unsigned short hb = f2bf(h);
        Hout[b * 256 + j] = hb;
        if (last) Yout[b * 256 + j] = hb;
      }
    }
    __syncthreads();                           // all 4 waves' h stores drained
    if (tid == 0)
      __hip_atomic_fetch_add(&prod[l * NT + t], 1, __ATOMIC_RELEASE, __HIP_MEMORY_SCOPE_AGENT);
  }
}

// ---------------- final projection ----------------
__global__ void final_proj(const unsigned short* __restrict__ Y,
                           const float* __restrict__ Wout,
                           const float* __restrict__ bout,
                           float* __restrict__ out) {
  int t = blockIdx.x;
  int tid = threadIdx.x;            // 128 = 64 b * 2 o
  int b = tid >> 1, o = tid & 1;
  const unsigned short* yrow = Y + (t * NB + b) * 256;
  const float* wr = Wout + o * 256;
  float s = bout[o];
  for (int k0 = 0; k0 < 256; k0 += 8) {
    short8 yv = *(const short8*)(yrow + k0);
#pragma unroll
    for (int e = 0; e < 8; ++e)
      s += bf2f(((unsigned short*)&yv)[e]) * wr[k0 + e];
  }
  out[(b * NT + t) * 2 + o] = 1.0f / (1.0f + __expf(-s));
}

extern "C" void kernel_launch(void* const* d_in, const int* in_sizes, int n_in,
                              void* d_out, int out_size, void* d_ws, size_t ws_size,
                              hipStream_t stream) {
  (void)in_sizes; (void)n_in; (void)out_size; (void)ws_size;
  const float* x    = (const float*)d_in[0];
  const float* Wih  = (const float*)d_in[1];
  const float* Whh  = (const float*)d_in[2];
  const float* bih  = (const float*)d_in[3];
  const float* bhh  = (const float*)d_in[4];
  const float* Wout = (const float*)d_in[5];
  const float* bout = (const float*)d_in[6];
  float* out = (float*)d_out;

  char* ws = (char*)d_ws;
  unsigned short* Wswz  = (unsigned short*)(ws + OFF_WSWZ);
  float*          Bias  = (float*)(ws + OFF_BIAS);
  unsigned short* Xbf   = (unsigned short*)(ws + OFF_XBF);
  unsigned short* Hring = (unsigned short*)(ws + OFF_HRING);
  unsigned short* Y     = (unsigned short*)(ws + OFF_Y);
  int*            prod  = (int*)(ws + OFF_PROD);
  int*            cons  = (int*)(ws + OFF_CONS);

  prep_w    <<<102400, 256, 0, stream>>>(Wih, Whh, Wswz);
  prep_bias <<<200,    256, 0, stream>>>(bih, bhh, Bias);
  prep_x    <<<16384,  256, 0, stream>>>(x, Xbf);
  zero_flags<<<100,    256, 0, stream>>>(prod);      // prod+cons contiguous, 25600 ints

  lstm_persistent<<<256, 256, 0, stream>>>(Wswz, Bias, Xbf, Hring, Y, prod, cons);

  final_proj<<<NT, 128, 0, stream>>>(Y, Wout, bout, out);
}

// Round 5
// 2963.911 us; speedup vs baseline: 4.4384x; 1.7994x over previous
//
#include <hip/hip_runtime.h>
#include <hip/hip_bf16.h>
#include <stdint.h>
#include <string.h>

// ---------------- problem constants ----------------
// B=64, T=256, D=H=256, L=50, O=2; K = 2H = 512 (concat [h_in; h_prev]); G = 4H = 1024
#define NB   64
#define NT   256
#define NH   256
#define NL   50
#define NK   512
#define NG   1024

typedef __attribute__((ext_vector_type(8)))  short   short8;
typedef __attribute__((ext_vector_type(8)))  __bf16  bf16x8;
typedef __attribute__((ext_vector_type(4)))  float   float4v;

__device__ __forceinline__ unsigned short f2bf(float f) {
  union { float f; uint32_t u; } v; v.f = f;
  uint32_t u = v.u;
  uint32_t r = (u + 0x7FFFu + ((u >> 16) & 1u)) >> 16;   // RNE
  return (unsigned short)r;
}
__device__ __forceinline__ float bf2f(unsigned short s) {
  union { uint32_t u; float f; } v; v.u = ((uint32_t)s) << 16;
  return v.f;
}
// fast, overflow-safe activations (tolerance 1e-2; v_exp/v_rcp ~1ulp)
__device__ __forceinline__ float sigmoid_f(float x) {
  return 1.0f / (1.0f + __expf(-x));
}
__device__ __forceinline__ float tanh_f(float x) {
  float e = __expf(-2.0f * __builtin_fabsf(x));   // in (0,1]
  float r = (1.0f - e) / (1.0f + e);
  return __builtin_copysignf(r, x);
}

// ---------------- workspace layout (bytes) ----------------
#define OFF_WSWZ  0
#define OFF_BIAS  52428800
#define OFF_XBF   52633600
#define OFF_HRING 61022208
#define OFF_Y     67575808
#define OFF_PROD  75964416
#define OFF_CONS  76015616
// total: 76,066,816 bytes

// ---------------- preprocessing ----------------
// Weight swizzle: Wswz[idx], idx = ((((l*16+c)*4+q)*16+kt)*64+lam)*8+j
// holds Wcat[g = q*256 + c*16 + (lam&15)][k = kt*32 + (lam>>4)*8 + j] as bf16.
// Exact MFMA B-fragment lane order (verified by R1-R3 pass).
__global__ void prep_w(const float* __restrict__ Wih, const float* __restrict__ Whh,
                       unsigned short* __restrict__ Wswz) {
  int idx = blockIdx.x * 256 + threadIdx.x;        // 26,214,400 total
  int j   = idx & 7;
  int lam = (idx >> 3) & 63;
  int kt  = (idx >> 9) & 15;
  int q   = (idx >> 13) & 3;
  int c   = (idx >> 15) & 15;
  int l   = idx >> 19;
  int k   = kt * 32 + (lam >> 4) * 8 + j;
  int g   = q * 256 + c * 16 + (lam & 15);
  float v = (k < 256) ? Wih[(l * NG + g) * 256 + k]
                      : Whh[(l * NG + g) * 256 + (k - 256)];
  Wswz[idx] = f2bf(v);
}

__global__ void prep_bias(const float* __restrict__ bih, const float* __restrict__ bhh,
                          float* __restrict__ Bias) {
  int idx = blockIdx.x * 256 + threadIdx.x;        // 51,200 total
  int col = idx & 15; int q = (idx >> 4) & 3; int c = (idx >> 6) & 15; int l = idx >> 10;
  int g = q * 256 + c * 16 + col;
  Bias[idx] = bih[l * NG + g] + bhh[l * NG + g];
}

__global__ void prep_x(const float* __restrict__ x, unsigned short* __restrict__ Xbf) {
  int idx = blockIdx.x * 256 + threadIdx.x;        // 4,194,304 total
  int d = idx & 255; int t = (idx >> 8) & 255; int b = idx >> 16;
  Xbf[(t * NB + b) * 256 + d] = f2bf(x[idx]);
}

__global__ void zero_flags(int* __restrict__ p) {
  p[blockIdx.x * 256 + threadIdx.x] = 0;           // 25,600 ints (prod+cons contiguous)
}

// ---------------- persistent LSTM kernel ----------------
// Grid 256 (56 exit): x=blockIdx&7 ~ XCD; XCD x hosts layers 7x..7x+6; the 4
// sibling WGs of a layer co-locate on one XCD. ~114KB LDS forces 1 WG/CU ->
// all 200 workers co-resident, 1 wave/SIMD, 512-VGPR budget holds each wave's
// 64KB weight chunk in VGPRs for all 256 timesteps.
// h exchange: 8B agent-scope RELAXED atomics (write-through -> coherence pt),
// so the prod release fence's L2 writeback finds no dirty h lines (cheap).
// prod: release add by each sibling; consumers leader-poll relaxed, one
// acquire fence, syncthreads broadcast.
#define RSTRIDE 81   // LDS row stride in 16B units; 81 % 8 == 1 -> conflict-free
#define HSTRIDE 264  // hout row stride in shorts (264*2 = 528 B, 16B-aligned rows)
__global__ __launch_bounds__(256, 1) void lstm_persistent(
    const unsigned short* __restrict__ Wswz,
    const float* __restrict__ Bias,
    const unsigned short* __restrict__ Xbf,
    unsigned short* __restrict__ Hring,
    unsigned short* __restrict__ Y,
    int* __restrict__ prod,
    int* __restrict__ cons) {
  int xcd = blockIdx.x & 7;
  int jj  = blockIdx.x >> 3;
  int l   = xcd * 7 + (jj >> 2);
  int w   = jj & 3;
  if (jj >= 28 || l >= NL) return;     // 56 idle WGs exit
  int tid = threadIdx.x;

  __shared__ unsigned short hc[64 * RSTRIDE * 8];     // 82,944 B staging
  __shared__ unsigned short hout[64 * HSTRIDE];       // 33,792 B epilogue bounce

  int wv   = tid >> 6;              // wave 0..3
  int ln   = tid & 63;
  int c    = w * 4 + wv;            // gate chunk 0..15 -> hidden units [c*16, c*16+16)
  int colg = ln & 15;
  int quad = ln >> 4;
  bool pvside = (wv & 1);           // staging: odd waves load h_prev half
  int  brb    = wv >> 1;            // staging row base parity

  // ---- one-time: weights into registers (64 x bf16x8 = 256 VGPRs/lane) ----
  bf16x8 wreg[64];
  {
    const unsigned short* wp = Wswz + (size_t)(l * 16 + c) * 32768 + ln * 8;
#pragma unroll
    for (int i = 0; i < 64; ++i)
      wreg[i] = *(const bf16x8*)(wp + i * 512);
  }
  float bv[4];
  {
    const float* bp = Bias + l * NG + c * 64;
#pragma unroll
    for (int q = 0; q < 4; ++q) bv[q] = bp[q * 16 + colg];
  }

  float cr[4][4] = {};              // cell state in registers
  int j = c * 16 + colg;
  bool last = (l == NL - 1);

  for (int t = 0; t < NT; ++t) {
    // ---- leader-poll: relaxed loads, one acquire fence ----
    if (tid == 0) {
      int* f1 = (l > 0) ? &prod[(l - 1) * NT + t] : nullptr;
      int* f2 = (t > 0) ? &prod[l * NT + (t - 1)] : nullptr;
      int* f3 = (!last && t >= 4) ? &cons[l * NT + (t - 4)] : nullptr;
      for (;;) {
        int a1 = f1 ? __hip_atomic_load(f1, __ATOMIC_RELAXED, __HIP_MEMORY_SCOPE_AGENT) : 4;
        int a2 = f2 ? __hip_atomic_load(f2, __ATOMIC_RELAXED, __HIP_MEMORY_SCOPE_AGENT) : 4;
        int a3 = f3 ? __hip_atomic_load(f3, __ATOMIC_RELAXED, __HIP_MEMORY_SCOPE_AGENT) : 4;
        if (a1 >= 4 && a2 >= 4 && a3 >= 4) break;
      }
      __builtin_amdgcn_fence(__ATOMIC_ACQUIRE, "agent");
    }
    __syncthreads();

    // ---- staging: prefetch 32x8B coherent loads (branch-free, wave-uniform) ----
    // per wave: rows b = i*2 + brb; even waves load In-half (k 0..255),
    // odd waves load Pv-half (k 256..511); 64 lanes x 8B cover one 512B half-row.
    {
      unsigned long long v[32];
      if (!pvside) {
        const unsigned short* In = (l == 0)
            ? (Xbf + t * (NB * 256))
            : (Hring + (((t & 3) * NL + (l - 1)) * NB) * 256);
#pragma unroll
        for (int i = 0; i < 32; ++i) {
          int b = i * 2 + brb;
          v[i] = __hip_atomic_load((const unsigned long long*)(In + b * 256 + ln * 4),
                                   __ATOMIC_RELAXED, __HIP_MEMORY_SCOPE_AGENT);
        }
      } else if (t > 0) {
        const unsigned short* Pv = Hring + ((((t - 1) & 3) * NL + l) * NB) * 256;
#pragma unroll
        for (int i = 0; i < 32; ++i) {
          int b = i * 2 + brb;
          v[i] = __hip_atomic_load((const unsigned long long*)(Pv + b * 256 + ln * 4),
                                   __ATOMIC_RELAXED, __HIP_MEMORY_SCOPE_AGENT);
        }
      } else {
#pragma unroll
        for (int i = 0; i < 32; ++i) v[i] = 0ull;
      }
      // LDS write: 16B-unit ku = pvside*32 + (ln>>1), 8B half = ln&1
      int ku   = (pvside ? 32 : 0) + (ln >> 1);
      int half = ln & 1;
#pragma unroll
      for (int i = 0; i < 32; ++i) {
        int b = i * 2 + brb;
        *(unsigned long long*)(hc + (b * RSTRIDE + ku) * 8 + half * 4) = v[i];
      }
    }
    __syncthreads();
    if (tid == 0 && l > 0)    // upstream slot consumed (ordered by the barrier above)
      __hip_atomic_fetch_add(&cons[(l - 1) * NT + t], 1, __ATOMIC_RELAXED, __HIP_MEMORY_SCOPE_AGENT);

    // ---- GEMM: 256 MFMAs/wave, weights from registers ----
    float4v acc[4][4];
#pragma unroll
    for (int q = 0; q < 4; ++q) {
      float4v f4 = {bv[q], bv[q], bv[q], bv[q]};
#pragma unroll
      for (int m = 0; m < 4; ++m) acc[m][q] = f4;
    }
#pragma unroll
    for (int kt = 0; kt < 16; ++kt) {
      bf16x8 a[4];
#pragma unroll
      for (int m = 0; m < 4; ++m)
        a[m] = *(const bf16x8*)(hc + ((m * 16 + colg) * RSTRIDE + kt * 4 + quad) * 8);
#pragma unroll
      for (int m = 0; m < 4; ++m)
#pragma unroll
        for (int q = 0; q < 4; ++q)
          acc[m][q] = __builtin_amdgcn_mfma_f32_16x16x32_bf16(a[m], wreg[q * 16 + kt], acc[m][q], 0, 0, 0);
    }

    // ---- epilogue: gates -> c,h ; scatter h into LDS bounce (own columns) ----
#pragma unroll
    for (int m = 0; m < 4; ++m) {
#pragma unroll
      for (int r = 0; r < 4; ++r) {
        int b = m * 16 + quad * 4 + r;
        float gi = sigmoid_f(acc[m][0][r]);
        float gf = sigmoid_f(acc[m][1][r]);
        float gg = tanh_f(acc[m][2][r]);
        float go = sigmoid_f(acc[m][3][r]);
        float cn = gf * cr[m][r] + gi * gg;   // cr starts 0 => t=0 correct
        cr[m][r] = cn;
        float h = go * tanh_f(cn);
        hout[b * HSTRIDE + j] = f2bf(h);
      }
    }
    __syncthreads();

    // ---- flush: ONLY this WG's 64 columns [w*64, w*64+64) of each row ----
    // 64 rows x 8 units(16B) = 512 units; 2 per thread; 8 consecutive lanes
    // cover one row's contiguous 128B -> coalesced segments.
    {
      unsigned short* Hout = Hring + (((t & 3) * NL + l) * NB) * 256;
      unsigned short* Yout = Y + (t * NB) * 256;
#pragma unroll
      for (int pass = 0; pass < 2; ++pass) {
        int u   = pass * 256 + tid;     // 0..511
        int b   = u >> 3;               // row 0..63
        int e   = u & 7;                // 16B unit within the 128B slice
        int col = w * 64 + e * 8;       // shorts
        union { short8 s; unsigned long long d[2]; } uu;
        uu.s = *(const short8*)(hout + b * HSTRIDE + col);
        unsigned long long* gp = (unsigned long long*)(Hout + b * 256 + col);
        __hip_atomic_store(gp + 0, uu.d[0], __ATOMIC_RELAXED, __HIP_MEMORY_SCOPE_AGENT);
        __hip_atomic_store(gp + 1, uu.d[1], __ATOMIC_RELAXED, __HIP_MEMORY_SCOPE_AGENT);
        if (last) *(short8*)(Yout + b * 256 + col) = uu.s;
      }
    }
    __syncthreads();                           // all threads' stores issued & drained
    if (tid == 0)
      __hip_atomic_fetch_add(&prod[l * NT + t], 1, __ATOMIC_RELEASE, __HIP_MEMORY_SCOPE_AGENT);
  }
}

// ---------------- final projection ----------------
__global__ void final_proj(const unsigned short* __restrict__ Y,
                           const float* __restrict__ Wout,
                           const float* __restrict__ bout,
                           float* __restrict__ out) {
  int t = blockIdx.x;
  int tid = threadIdx.x;            // 128 = 64 b * 2 o
  int b = tid >> 1, o = tid & 1;
  const unsigned short* yrow = Y + (t * NB + b) * 256;
  const float* wr = Wout + o * 256;
  float s = bout[o];
  for (int k0 = 0; k0 < 256; k0 += 8) {
    short8 yv = *(const short8*)(yrow + k0);
#pragma unroll
    for (int e = 0; e < 8; ++e)
      s += bf2f(((unsigned short*)&yv)[e]) * wr[k0 + e];
  }
  out[(b * NT + t) * 2 + o] = 1.0f / (1.0f + __expf(-s));
}

extern "C" void kernel_launch(void* const* d_in, const int* in_sizes, int n_in,
                              void* d_out, int out_size, void* d_ws, size_t ws_size,
                              hipStream_t stream) {
  (void)in_sizes; (void)n_in; (void)out_size; (void)ws_size;
  const float* x    = (const float*)d_in[0];
  const float* Wih  = (const float*)d_in[1];
  const float* Whh  = (const float*)d_in[2];
  const float* bih  = (const float*)d_in[3];
  const float* bhh  = (const float*)d_in[4];
  const float* Wout = (const float*)d_in[5];
  const float* bout = (const float*)d_in[6];
  float* out = (float*)d_out;

  char* ws = (char*)d_ws;
  unsigned short* Wswz  = (unsigned short*)(ws + OFF_WSWZ);
  float*          Bias  = (float*)(ws + OFF_BIAS);
  unsigned short* Xbf   = (unsigned short*)(ws + OFF_XBF);
  unsigned short* Hring = (unsigned short*)(ws + OFF_HRING);
  unsigned short* Y     = (unsigned short*)(ws + OFF_Y);
  int*            prod  = (int*)(ws + OFF_PROD);
  int*            cons  = (int*)(ws + OFF_CONS);

  prep_w    <<<102400, 256, 0, stream>>>(Wih, Whh, Wswz);
  prep_bias <<<200,    256, 0, stream>>>(bih, bhh, Bias);
  prep_x    <<<16384,  256, 0, stream>>>(x, Xbf);
  zero_flags<<<100,    256, 0, stream>>>(prod);      // prod+cons contiguous, 25600 ints

  lstm_persistent<<<256, 256, 0, stream>>>(Wswz, Bias, Xbf, Hring, Y, prod, cons);

  final_proj<<<NT, 128, 0, stream>>>(Y, Wout, bout, out);
}

// Round 6
// 2539.125 us; speedup vs baseline: 5.1809x; 1.1673x over previous
//
#include <hip/hip_runtime.h>
#include <hip/hip_bf16.h>
#include <stdint.h>
#include <string.h>

// ---------------- problem constants ----------------
// B=64, T=256, D=H=256, L=50, O=2; K = 2H = 512 (concat [h_in; h_prev]); G = 4H = 1024
#define NB   64
#define NT   256
#define NH   256
#define NL   50
#define NK   512
#define NG   1024

typedef __attribute__((ext_vector_type(8)))  short   short8;
typedef __attribute__((ext_vector_type(8)))  __bf16  bf16x8;
typedef __attribute__((ext_vector_type(4)))  float   float4v;

__device__ __forceinline__ unsigned short f2bf(float f) {
  union { float f; uint32_t u; } v; v.f = f;
  uint32_t u = v.u;
  uint32_t r = (u + 0x7FFFu + ((u >> 16) & 1u)) >> 16;   // RNE
  return (unsigned short)r;
}
__device__ __forceinline__ float bf2f(unsigned short s) {
  union { uint32_t u; float f; } v; v.u = ((uint32_t)s) << 16;
  return v.f;
}
// fast, overflow-safe activations (tolerance 1e-2; v_exp/v_rcp ~1ulp)
__device__ __forceinline__ float sigmoid_f(float x) {
  return 1.0f / (1.0f + __expf(-x));
}
__device__ __forceinline__ float tanh_f(float x) {
  float e = __expf(-2.0f * __builtin_fabsf(x));   // in (0,1]
  float r = (1.0f - e) / (1.0f + e);
  return __builtin_copysignf(r, x);
}

// ---------------- workspace layout (bytes) ----------------
#define OFF_WSWZ  0
#define OFF_BIAS  52428800
#define OFF_XBF   52633600
#define OFF_HRING 61022208
#define OFF_Y     67575808
#define OFF_PROD  75964416
#define OFF_CONS  76015616
// total: 76,066,816 bytes

// ---------------- preprocessing ----------------
// Weight swizzle: Wswz[idx], idx = ((((l*16+c)*4+q)*16+kt)*64+lam)*8+j
// holds Wcat[g = q*256 + c*16 + (lam&15)][k = kt*32 + (lam>>4)*8 + j] as bf16.
// Exact MFMA B-fragment lane order (verified by R1-R5 pass).
__global__ void prep_w(const float* __restrict__ Wih, const float* __restrict__ Whh,
                       unsigned short* __restrict__ Wswz) {
  int idx = blockIdx.x * 256 + threadIdx.x;        // 26,214,400 total
  int j   = idx & 7;
  int lam = (idx >> 3) & 63;
  int kt  = (idx >> 9) & 15;
  int q   = (idx >> 13) & 3;
  int c   = (idx >> 15) & 15;
  int l   = idx >> 19;
  int k   = kt * 32 + (lam >> 4) * 8 + j;
  int g   = q * 256 + c * 16 + (lam & 15);
  float v = (k < 256) ? Wih[(l * NG + g) * 256 + k]
                      : Whh[(l * NG + g) * 256 + (k - 256)];
  Wswz[idx] = f2bf(v);
}

__global__ void prep_bias(const float* __restrict__ bih, const float* __restrict__ bhh,
                          float* __restrict__ Bias) {
  int idx = blockIdx.x * 256 + threadIdx.x;        // 51,200 total
  int col = idx & 15; int q = (idx >> 4) & 3; int c = (idx >> 6) & 15; int l = idx >> 10;
  int g = q * 256 + c * 16 + col;
  Bias[idx] = bih[l * NG + g] + bhh[l * NG + g];
}

__global__ void prep_x(const float* __restrict__ x, unsigned short* __restrict__ Xbf) {
  int idx = blockIdx.x * 256 + threadIdx.x;        // 4,194,304 total
  int d = idx & 255; int t = (idx >> 8) & 255; int b = idx >> 16;
  Xbf[(t * NB + b) * 256 + d] = f2bf(x[idx]);
}

__global__ void zero_flags(int* __restrict__ p) {
  p[blockIdx.x * 256 + threadIdx.x] = 0;           // 25,600 ints (prod+cons contiguous)
}

// all 64 lanes spin on one broadcast address; wave-uniform exit; no fences —
// data travels via coherence-point atomics, ordering via barrier waitcnt.
__device__ __forceinline__ void wave_wait4(int* p) {
  while (__hip_atomic_load(p, __ATOMIC_RELAXED, __HIP_MEMORY_SCOPE_AGENT) < 4)
    ;
}

// ---------------- persistent LSTM kernel ----------------
// Grid 256 (56 exit): x=blockIdx&7 ~ XCD; XCD x hosts layers 7x..7x+6; the 4
// sibling WGs of a layer co-locate on one XCD. ~114KB LDS forces 1 WG/CU ->
// all 200 workers co-resident, 1 wave/SIMD, 512-reg budget holds each wave's
// 64KB weight chunk for all 256 timesteps.
// h exchange: 8B agent-scope RELAXED atomics (write-through, coherence point).
// Flags: RELAXED agent atomics only — no acquire/release fences anywhere.
// Ordering argument: producer's flush stores are sc-coherent and drained by
// the __syncthreads() (s_waitcnt vmcnt(0)) before the prod add issues; the
// consumer's h loads are sc-coherent, issued only after its poll loop exits.
#define RSTRIDE 81   // LDS row stride in 16B units; 81 % 8 == 1 -> conflict-free
#define HSTRIDE 264  // hout row stride in shorts (264*2 = 528 B, 16B-aligned rows)
__global__ __launch_bounds__(256, 1) void lstm_persistent(
    const unsigned short* __restrict__ Wswz,
    const float* __restrict__ Bias,
    const unsigned short* __restrict__ Xbf,
    unsigned short* __restrict__ Hring,
    unsigned short* __restrict__ Y,
    int* __restrict__ prod,
    int* __restrict__ cons) {
  int xcd = blockIdx.x & 7;
  int jj  = blockIdx.x >> 3;
  int l   = xcd * 7 + (jj >> 2);
  int w   = jj & 3;
  if (jj >= 28 || l >= NL) return;     // 56 idle WGs exit
  int tid = threadIdx.x;

  __shared__ unsigned short hc[64 * RSTRIDE * 8];     // 82,944 B staging
  __shared__ unsigned short hout[64 * HSTRIDE];       // 33,792 B epilogue bounce

  int wv   = tid >> 6;              // wave 0..3
  int ln   = tid & 63;
  int c    = w * 4 + wv;            // gate chunk 0..15 -> hidden units [c*16, c*16+16)
  int colg = ln & 15;
  int quad = ln >> 4;
  bool pvside = (wv & 1);           // staging: odd waves load h_prev half
  int  brb    = wv >> 1;            // staging row base parity

  // ---- one-time: weights into registers (64 x bf16x8 = 256 VGPRs/lane) ----
  bf16x8 wreg[64];
  {
    const unsigned short* wp = Wswz + (size_t)(l * 16 + c) * 32768 + ln * 8;
#pragma unroll
    for (int i = 0; i < 64; ++i)
      wreg[i] = *(const bf16x8*)(wp + i * 512);
  }
  float bv[4];
  {
    const float* bp = Bias + l * NG + c * 64;
#pragma unroll
    for (int q = 0; q < 4; ++q) bv[q] = bp[q * 16 + colg];
  }

  float cr[4][4] = {};              // cell state in registers
  int j = c * 16 + colg;
  bool last = (l == NL - 1);

  for (int t = 0; t < NT; ++t) {
    // ---- per-wave dependency gate + prefetched staging loads ----
    // Even waves own the In half (k 0..255): gated on prod[l-1][t].
    // Odd  waves own the Pv half (k 256..511): gated on prod[l][t-1].
    // The two flag RTTs and the two 32KB load streams overlap fully.
    {
      unsigned long long v[32];
      if (!pvside) {
        if (l > 0) wave_wait4(&prod[(l - 1) * NT + t]);
        const unsigned short* In = (l == 0)
            ? (Xbf + t * (NB * 256))
            : (Hring + (((t & 3) * NL + (l - 1)) * NB) * 256);
#pragma unroll
        for (int i = 0; i < 32; ++i) {
          int b = i * 2 + brb;
          v[i] = __hip_atomic_load((const unsigned long long*)(In + b * 256 + ln * 4),
                                   __ATOMIC_RELAXED, __HIP_MEMORY_SCOPE_AGENT);
        }
      } else if (t > 0) {
        wave_wait4(&prod[l * NT + (t - 1)]);
        const unsigned short* Pv = Hring + ((((t - 1) & 3) * NL + l) * NB) * 256;
#pragma unroll
        for (int i = 0; i < 32; ++i) {
          int b = i * 2 + brb;
          v[i] = __hip_atomic_load((const unsigned long long*)(Pv + b * 256 + ln * 4),
                                   __ATOMIC_RELAXED, __HIP_MEMORY_SCOPE_AGENT);
        }
      } else {
#pragma unroll
        for (int i = 0; i < 32; ++i) v[i] = 0ull;
      }
      // LDS write: 16B-unit ku = pvside*32 + (ln>>1), 8B half = ln&1
      int ku   = (pvside ? 32 : 0) + (ln >> 1);
      int half = ln & 1;
#pragma unroll
      for (int i = 0; i < 32; ++i) {
        int b = i * 2 + brb;
        *(unsigned long long*)(hc + (b * RSTRIDE + ku) * 8 + half * 4) = v[i];
      }
    }
    __syncthreads();
    if (tid == 0 && l > 0)    // upstream slot consumed (loads completed before barrier)
      __hip_atomic_fetch_add(&cons[(l - 1) * NT + t], 1, __ATOMIC_RELAXED, __HIP_MEMORY_SCOPE_AGENT);

    // ---- GEMM: 256 MFMAs/wave, weights from registers ----
    float4v acc[4][4];
#pragma unroll
    for (int q = 0; q < 4; ++q) {
      float4v f4 = {bv[q], bv[q], bv[q], bv[q]};
#pragma unroll
      for (int m = 0; m < 4; ++m) acc[m][q] = f4;
    }
#pragma unroll
    for (int kt = 0; kt < 16; ++kt) {
      bf16x8 a[4];
#pragma unroll
      for (int m = 0; m < 4; ++m)
        a[m] = *(const bf16x8*)(hc + ((m * 16 + colg) * RSTRIDE + kt * 4 + quad) * 8);
#pragma unroll
      for (int m = 0; m < 4; ++m)
#pragma unroll
        for (int q = 0; q < 4; ++q)
          acc[m][q] = __builtin_amdgcn_mfma_f32_16x16x32_bf16(a[m], wreg[q * 16 + kt], acc[m][q], 0, 0, 0);
    }

    // ---- epilogue: gates -> c,h ; scatter h into LDS bounce (own columns) ----
#pragma unroll
    for (int m = 0; m < 4; ++m) {
#pragma unroll
      for (int r = 0; r < 4; ++r) {
        int b = m * 16 + quad * 4 + r;
        float gi = sigmoid_f(acc[m][0][r]);
        float gf = sigmoid_f(acc[m][1][r]);
        float gg = tanh_f(acc[m][2][r]);
        float go = sigmoid_f(acc[m][3][r]);
        float cn = gf * cr[m][r] + gi * gg;   // cr starts 0 => t=0 correct
        cr[m][r] = cn;
        float h = go * tanh_f(cn);
        hout[b * HSTRIDE + j] = f2bf(h);
      }
    }
    // ---- ring backpressure: gates only the flush; usually already satisfied.
    // Wave 0 polls while waves 1-3 finish their epilogue; barrier joins.
    if (wv == 0 && !last && t >= 4) wave_wait4(&cons[l * NT + (t - 4)]);
    __syncthreads();

    // ---- flush: ONLY this WG's 64 columns [w*64, w*64+64) of each row ----
    {
      unsigned short* Hout = Hring + (((t & 3) * NL + l) * NB) * 256;
      unsigned short* Yout = Y + (t * NB) * 256;
#pragma unroll
      for (int pass = 0; pass < 2; ++pass) {
        int u   = pass * 256 + tid;     // 0..511
        int b   = u >> 3;               // row 0..63
        int e   = u & 7;                // 16B unit within the 128B slice
        int col = w * 64 + e * 8;       // shorts
        union { short8 s; unsigned long long d[2]; } uu;
        uu.s = *(const short8*)(hout + b * HSTRIDE + col);
        unsigned long long* gp = (unsigned long long*)(Hout + b * 256 + col);
        __hip_atomic_store(gp + 0, uu.d[0], __ATOMIC_RELAXED, __HIP_MEMORY_SCOPE_AGENT);
        __hip_atomic_store(gp + 1, uu.d[1], __ATOMIC_RELAXED, __HIP_MEMORY_SCOPE_AGENT);
        if (last) *(short8*)(Yout + b * 256 + col) = uu.s;
      }
    }
    __syncthreads();                 // per-wave vmcnt(0) at barrier => all stores at coherence pt
    if (tid == 0)
      __hip_atomic_fetch_add(&prod[l * NT + t], 1, __ATOMIC_RELAXED, __HIP_MEMORY_SCOPE_AGENT);
  }
}

// ---------------- final projection ----------------
__global__ void final_proj(const unsigned short* __restrict__ Y,
                           const float* __restrict__ Wout,
                           const float* __restrict__ bout,
                           float* __restrict__ out) {
  int t = blockIdx.x;
  int tid = threadIdx.x;            // 128 = 64 b * 2 o
  int b = tid >> 1, o = tid & 1;
  const unsigned short* yrow = Y + (t * NB + b) * 256;
  const float* wr = Wout + o * 256;
  float s = bout[o];
  for (int k0 = 0; k0 < 256; k0 += 8) {
    short8 yv = *(const short8*)(yrow + k0);
#pragma unroll
    for (int e = 0; e < 8; ++e)
      s += bf2f(((unsigned short*)&yv)[e]) * wr[k0 + e];
  }
  out[(b * NT + t) * 2 + o] = 1.0f / (1.0f + __expf(-s));
}

extern "C" void kernel_launch(void* const* d_in, const int* in_sizes, int n_in,
                              void* d_out, int out_size, void* d_ws, size_t ws_size,
                              hipStream_t stream) {
  (void)in_sizes; (void)n_in; (void)out_size; (void)ws_size;
  const float* x    = (const float*)d_in[0];
  const float* Wih  = (const float*)d_in[1];
  const float* Whh  = (const float*)d_in[2];
  const float* bih  = (const float*)d_in[3];
  const float* bhh  = (const float*)d_in[4];
  const float* Wout = (const float*)d_in[5];
  const float* bout = (const float*)d_in[6];
  float* out = (float*)d_out;

  char* ws = (char*)d_ws;
  unsigned short* Wswz  = (unsigned short*)(ws + OFF_WSWZ);
  float*          Bias  = (float*)(ws + OFF_BIAS);
  unsigned short* Xbf   = (unsigned short*)(ws + OFF_XBF);
  unsigned short* Hring = (unsigned short*)(ws + OFF_HRING);
  unsigned short* Y     = (unsigned short*)(ws + OFF_Y);
  int*            prod  = (int*)(ws + OFF_PROD);
  int*            cons  = (int*)(ws + OFF_CONS);

  prep_w    <<<102400, 256, 0, stream>>>(Wih, Whh, Wswz);
  prep_bias <<<200,    256, 0, stream>>>(bih, bhh, Bias);
  prep_x    <<<16384,  256, 0, stream>>>(x, Xbf);
  zero_flags<<<100,    256, 0, stream>>>(prod);      // prod+cons contiguous, 25600 ints

  lstm_persistent<<<256, 256, 0, stream>>>(Wswz, Bias, Xbf, Hring, Y, prod, cons);

  final_proj<<<NT, 128, 0, stream>>>(Y, Wout, bout, out);
}

// Round 7
// 2406.944 us; speedup vs baseline: 5.4654x; 1.0549x over previous
//
#include <hip/hip_runtime.h>
#include <hip/hip_bf16.h>
#include <stdint.h>
#include <string.h>

// ---------------- problem constants ----------------
// B=64, T=256, D=H=256, L=50, O=2; K = 2H = 512 (concat [h_in; h_prev]); G = 4H = 1024
#define NB   64
#define NT   256
#define NH   256
#define NL   50
#define NK   512
#define NG   1024

typedef __attribute__((ext_vector_type(8)))  short   short8;
typedef __attribute__((ext_vector_type(8)))  __bf16  bf16x8;
typedef __attribute__((ext_vector_type(4)))  float   float4v;
typedef __attribute__((ext_vector_type(4)))  int     int4v;

__device__ __forceinline__ unsigned short f2bf(float f) {
  union { float f; uint32_t u; } v; v.f = f;
  uint32_t u = v.u;
  uint32_t r = (u + 0x7FFFu + ((u >> 16) & 1u)) >> 16;   // RNE
  return (unsigned short)r;
}
__device__ __forceinline__ float bf2f(unsigned short s) {
  union { uint32_t u; float f; } v; v.u = ((uint32_t)s) << 16;
  return v.f;
}
// fast, overflow-safe activations (tolerance 1e-2; v_exp/v_rcp ~1ulp)
__device__ __forceinline__ float sigmoid_f(float x) {
  return 1.0f / (1.0f + __expf(-x));
}
__device__ __forceinline__ float tanh_f(float x) {
  float e = __expf(-2.0f * __builtin_fabsf(x));   // in (0,1]
  float r = (1.0f - e) / (1.0f + e);
  return __builtin_copysignf(r, x);
}

// ---- coherent, COALESCED 16B ops (sc1 = agent scope, LLC-direct; same
// coherence point the validated 8B atomics used, but wave-coalescable) ----
__device__ __forceinline__ short8 ldg_sc1_b128(const unsigned short* p) {
  short8 r;
  asm volatile("global_load_dwordx4 %0, %1, off sc1" : "=v"(r) : "v"(p) : "memory");
  return r;
}
__device__ __forceinline__ void stg_sc1_b128(unsigned short* p, short8 v) {
  asm volatile("global_store_dwordx4 %0, %1, off sc1" :: "v"(p), "v"(v) : "memory");
}
__device__ __forceinline__ void wait_vm0() {
  asm volatile("s_waitcnt vmcnt(0)" ::: "memory");
}
// poll 4 per-WG flags with ONE 16B coherent load (all lanes same addr -> 1 txn)
__device__ __forceinline__ void wave_wait_all4(const int* p) {
  for (;;) {
    int4v f;
    asm volatile("global_load_dwordx4 %0, %1, off sc1\n\ts_waitcnt vmcnt(0)"
                 : "=v"(f) : "v"(p) : "memory");
    if ((f[0] & f[1] & f[2] & f[3]) != 0) break;
  }
}

// ---------------- workspace layout (bytes) ----------------
#define OFF_WSWZ  0
#define OFF_BIAS  52428800
#define OFF_XBF   52633600
#define OFF_HRING 61022208
#define OFF_Y     67575808
#define OFF_PROD  75964416
#define OFF_CONS  76169216
// total: 76,374,016 bytes  (prod4/cons4: 50*256*4 ints = 204,800 B each)

// ---------------- preprocessing ----------------
// Weight swizzle: Wswz[idx], idx = ((((l*16+c)*4+q)*16+kt)*64+lam)*8+j
// holds Wcat[g = q*256 + c*16 + (lam&15)][k = kt*32 + (lam>>4)*8 + j] as bf16.
// Exact MFMA B-fragment lane order (verified R1-R6).
__global__ void prep_w(const float* __restrict__ Wih, const float* __restrict__ Whh,
                       unsigned short* __restrict__ Wswz) {
  int idx = blockIdx.x * 256 + threadIdx.x;        // 26,214,400 total
  int j   = idx & 7;
  int lam = (idx >> 3) & 63;
  int kt  = (idx >> 9) & 15;
  int q   = (idx >> 13) & 3;
  int c   = (idx >> 15) & 15;
  int l   = idx >> 19;
  int k   = kt * 32 + (lam >> 4) * 8 + j;
  int g   = q * 256 + c * 16 + (lam & 15);
  float v = (k < 256) ? Wih[(l * NG + g) * 256 + k]
                      : Whh[(l * NG + g) * 256 + (k - 256)];
  Wswz[idx] = f2bf(v);
}

__global__ void prep_bias(const float* __restrict__ bih, const float* __restrict__ bhh,
                          float* __restrict__ Bias) {
  int idx = blockIdx.x * 256 + threadIdx.x;        // 51,200 total
  int col = idx & 15; int q = (idx >> 4) & 3; int c = (idx >> 6) & 15; int l = idx >> 10;
  int g = q * 256 + c * 16 + col;
  Bias[idx] = bih[l * NG + g] + bhh[l * NG + g];
}

__global__ void prep_x(const float* __restrict__ x, unsigned short* __restrict__ Xbf) {
  int idx = blockIdx.x * 256 + threadIdx.x;        // 4,194,304 total
  int d = idx & 255; int t = (idx >> 8) & 255; int b = idx >> 16;
  Xbf[(t * NB + b) * 256 + d] = f2bf(x[idx]);
}

__global__ void zero_flags(int* __restrict__ p) {
  p[blockIdx.x * 256 + threadIdx.x] = 0;           // 102,400 ints (prod4+cons4)
}

// ---------------- persistent LSTM kernel ----------------
// Grid 256 (56 exit): x=blockIdx&7 ~ XCD (locality heuristic only; correctness
// never depends on it). ~114KB LDS forces 1 WG/CU -> all 200 workers
// co-resident; each wave's 64KB weight chunk register-resident for all 256 t.
// h exchange: coalesced 16B sc1 loads/stores (LLC coherence point).
// Flags: per-WG stores prod4[l][t][w]=1 (no RMW serialization); consumers
// poll the 4-int vector with one 16B sc1 load. Ordering: producer's h stores
// drain at __syncthreads (vmcnt 0) before the flag store issues; consumer's
// h loads issue only after its poll detects all 4 flags. (Mechanism validated
// by R5/R6 passes; this round only re-encodes the same traffic.)
#define RSTRIDE 81   // LDS row stride in 16B units; 81 % 8 == 1 -> conflict-free
#define HSTRIDE 264  // hout row stride in shorts (16B-aligned rows)
__global__ __launch_bounds__(256, 1) void lstm_persistent(
    const unsigned short* __restrict__ Wswz,
    const float* __restrict__ Bias,
    const unsigned short* __restrict__ Xbf,
    unsigned short* __restrict__ Hring,
    unsigned short* __restrict__ Y,
    int* __restrict__ prod4,
    int* __restrict__ cons4) {
  int xcd = blockIdx.x & 7;
  int jj  = blockIdx.x >> 3;
  int l   = xcd * 7 + (jj >> 2);
  int w   = jj & 3;
  if (jj >= 28 || l >= NL) return;     // 56 idle WGs exit
  int tid = threadIdx.x;

  __shared__ unsigned short hc[64 * RSTRIDE * 8];     // 82,944 B staging
  __shared__ unsigned short hout[64 * HSTRIDE];       // 33,792 B epilogue bounce

  int wv   = tid >> 6;              // wave 0..3
  int ln   = tid & 63;
  int c    = w * 4 + wv;            // gate chunk 0..15 -> hidden units [c*16, c*16+16)
  int colg = ln & 15;
  int quad = ln >> 4;
  bool pvside = (wv & 1);           // staging: odd waves load h_prev half
  int  brb    = wv >> 1;            // staging row-group parity

  // ---- one-time: weights into registers (64 x bf16x8 = 256 VGPRs/lane) ----
  bf16x8 wreg[64];
  {
    const unsigned short* wp = Wswz + (size_t)(l * 16 + c) * 32768 + ln * 8;
#pragma unroll
    for (int i = 0; i < 64; ++i)
      wreg[i] = *(const bf16x8*)(wp + i * 512);
  }
  float bv[4];
  {
    const float* bp = Bias + l * NG + c * 64;
#pragma unroll
    for (int q = 0; q < 4; ++q) bv[q] = bp[q * 16 + colg];
  }

  float cr[4][4] = {};              // cell state in registers
  int j = c * 16 + colg;
  bool last = (l == NL - 1);

  for (int t = 0; t < NT; ++t) {
    // ---- per-wave dependency gate + coalesced staging loads ----
    // Even waves own the In half (k 0..255): gated on prod4[l-1][t][0..3].
    // Odd  waves own the Pv half (k 256..511): gated on prod4[l][t-1][0..3].
    // Per iteration a wave loads 2 half-rows (64 lanes x 16B = 1KB coalesced).
    {
      short8 v[16];
      int e  = ln & 31;             // 16B unit within a 512B half-row
      int rs = ln >> 5;             // row parity within the pair
      if (!pvside) {
        if (l > 0) wave_wait_all4(&prod4[((l - 1) * NT + t) * 4]);
        const unsigned short* In = (l == 0)
            ? (Xbf + t * (NB * 256))
            : (Hring + (((t & 3) * NL + (l - 1)) * NB) * 256);
#pragma unroll
        for (int i = 0; i < 16; ++i) {
          int b = i * 4 + brb * 2 + rs;
          v[i] = ldg_sc1_b128(In + b * 256 + e * 8);
        }
      } else if (t > 0) {
        wave_wait_all4(&prod4[(l * NT + (t - 1)) * 4]);
        const unsigned short* Pv = Hring + ((((t - 1) & 3) * NL + l) * NB) * 256;
#pragma unroll
        for (int i = 0; i < 16; ++i) {
          int b = i * 4 + brb * 2 + rs;
          v[i] = ldg_sc1_b128(Pv + b * 256 + e * 8);
        }
      } else {
#pragma unroll
        for (int i = 0; i < 16; ++i) v[i] = short8{0, 0, 0, 0, 0, 0, 0, 0};
      }
      wait_vm0();                   // all 16 loads landed
      int kb = (pvside ? 32 : 0) + e;
#pragma unroll
      for (int i = 0; i < 16; ++i) {
        int b = i * 4 + brb * 2 + rs;
        *(short8*)(hc + (b * RSTRIDE + kb) * 8) = v[i];
      }
    }
    __syncthreads();
    if (tid == 0 && l > 0)    // upstream slot consumed (loads done before barrier)
      __hip_atomic_store(&cons4[((l - 1) * NT + t) * 4 + w], 1,
                         __ATOMIC_RELAXED, __HIP_MEMORY_SCOPE_AGENT);

    // ---- GEMM: 256 MFMAs/wave, weights from registers ----
    float4v acc[4][4];
#pragma unroll
    for (int q = 0; q < 4; ++q) {
      float4v f4 = {bv[q], bv[q], bv[q], bv[q]};
#pragma unroll
      for (int m = 0; m < 4; ++m) acc[m][q] = f4;
    }
#pragma unroll
    for (int kt = 0; kt < 16; ++kt) {
      bf16x8 a[4];
#pragma unroll
      for (int m = 0; m < 4; ++m)
        a[m] = *(const bf16x8*)(hc + ((m * 16 + colg) * RSTRIDE + kt * 4 + quad) * 8);
#pragma unroll
      for (int m = 0; m < 4; ++m)
#pragma unroll
        for (int q = 0; q < 4; ++q)
          acc[m][q] = __builtin_amdgcn_mfma_f32_16x16x32_bf16(a[m], wreg[q * 16 + kt], acc[m][q], 0, 0, 0);
    }

    // ---- epilogue: gates -> c,h ; scatter h into LDS bounce (own 16 cols) ----
#pragma unroll
    for (int m = 0; m < 4; ++m) {
#pragma unroll
      for (int r = 0; r < 4; ++r) {
        int b = m * 16 + quad * 4 + r;
        float gi = sigmoid_f(acc[m][0][r]);
        float gf = sigmoid_f(acc[m][1][r]);
        float gg = tanh_f(acc[m][2][r]);
        float go = sigmoid_f(acc[m][3][r]);
        float cn = gf * cr[m][r] + gi * gg;   // cr starts 0 => t=0 correct
        cr[m][r] = cn;
        float h = go * tanh_f(cn);
        hout[b * HSTRIDE + j] = f2bf(h);
      }
    }
    // ---- ring backpressure: gates only the flush; usually pre-satisfied.
    if (wv == 0 && !last && t >= 4) wave_wait_all4(&cons4[(l * NT + (t - 4)) * 4]);
    __syncthreads();

    // ---- flush: this WG's 64 columns of each row, coalesced 16B sc1 stores ----
    {
      unsigned short* Hout = Hring + (((t & 3) * NL + l) * NB) * 256;
      unsigned short* Yout = Y + (t * NB) * 256;
#pragma unroll
      for (int pass = 0; pass < 2; ++pass) {
        int u   = pass * 256 + tid;     // 0..511
        int b   = u >> 3;               // row 0..63
        int e8  = u & 7;                // 16B unit within the 128B slice
        int col = w * 64 + e8 * 8;      // shorts
        short8 hv = *(const short8*)(hout + b * HSTRIDE + col);
        stg_sc1_b128(Hout + b * 256 + col, hv);
        if (last) *(short8*)(Yout + b * 256 + col) = hv;
      }
    }
    __syncthreads();                 // vmcnt(0) at barrier => stores at coherence pt
    if (tid == 0)
      __hip_atomic_store(&prod4[(l * NT + t) * 4 + w], 1,
                         __ATOMIC_RELAXED, __HIP_MEMORY_SCOPE_AGENT);
  }
}

// ---------------- final projection ----------------
__global__ void final_proj(const unsigned short* __restrict__ Y,
                           const float* __restrict__ Wout,
                           const float* __restrict__ bout,
                           float* __restrict__ out) {
  int t = blockIdx.x;
  int tid = threadIdx.x;            // 128 = 64 b * 2 o
  int b = tid >> 1, o = tid & 1;
  const unsigned short* yrow = Y + (t * NB + b) * 256;
  const float* wr = Wout + o * 256;
  float s = bout[o];
  for (int k0 = 0; k0 < 256; k0 += 8) {
    short8 yv = *(const short8*)(yrow + k0);
#pragma unroll
    for (int e = 0; e < 8; ++e)
      s += bf2f(((unsigned short*)&yv)[e]) * wr[k0 + e];
  }
  out[(b * NT + t) * 2 + o] = 1.0f / (1.0f + __expf(-s));
}

extern "C" void kernel_launch(void* const* d_in, const int* in_sizes, int n_in,
                              void* d_out, int out_size, void* d_ws, size_t ws_size,
                              hipStream_t stream) {
  (void)in_sizes; (void)n_in; (void)out_size; (void)ws_size;
  const float* x    = (const float*)d_in[0];
  const float* Wih  = (const float*)d_in[1];
  const float* Whh  = (const float*)d_in[2];
  const float* bih  = (const float*)d_in[3];
  const float* bhh  = (const float*)d_in[4];
  const float* Wout = (const float*)d_in[5];
  const float* bout = (const float*)d_in[6];
  float* out = (float*)d_out;

  char* ws = (char*)d_ws;
  unsigned short* Wswz  = (unsigned short*)(ws + OFF_WSWZ);
  float*          Bias  = (float*)(ws + OFF_BIAS);
  unsigned short* Xbf   = (unsigned short*)(ws + OFF_XBF);
  unsigned short* Hring = (unsigned short*)(ws + OFF_HRING);
  unsigned short* Y     = (unsigned short*)(ws + OFF_Y);
  int*            prod4 = (int*)(ws + OFF_PROD);
  int*            cons4 = (int*)(ws + OFF_CONS);

  prep_w    <<<102400, 256, 0, stream>>>(Wih, Whh, Wswz);
  prep_bias <<<200,    256, 0, stream>>>(bih, bhh, Bias);
  prep_x    <<<16384,  256, 0, stream>>>(x, Xbf);
  zero_flags<<<400,    256, 0, stream>>>(prod4);     // prod4+cons4 contiguous

  lstm_persistent<<<256, 256, 0, stream>>>(Wswz, Bias, Xbf, Hring, Y, prod4, cons4);

  final_proj<<<NT, 128, 0, stream>>>(Y, Wout, bout, out);
}